// Round 1
// baseline (87.407 us; speedup 1.0000x reference)
//
#include <hip/hip_runtime.h>
#include <math.h>

#define NATOMS 21
#define DESC 210
#define NTRAIN 4096
#define NM 128

// constants from reference
#define SIGC 10.0f
#define CC 0.0f
#define STDC 1.0f
// q = sqrt(5)/sig
#define QS 0.22360679774997896f
// 5/(3*sig^2)
#define KE 0.016666666666666666f

__device__ __forceinline__ void pair_ij(int p, int& i, int& j) {
    // p = i*(i-1)/2 + j, 0 <= j < i, i in [1, NATOMS-1]
    int ii = (int)((1.0f + sqrtf(1.0f + 8.0f * (float)p)) * 0.5f);
    while (ii * (ii - 1) / 2 > p) --ii;
    while ((ii + 1) * ii / 2 <= p) ++ii;
    i = ii;
    j = p - ii * (ii - 1) / 2;
}

// A: per-molecule pair descriptors. aT[p*128+m] = q/r_p, asq[m] = sum_p a^2
__global__ __launch_bounds__(256) void k_desc(const float* __restrict__ Rs,
                                              float* __restrict__ aT,
                                              float* __restrict__ asq) {
    const int m = blockIdx.x;
    __shared__ float R[NATOMS * 3];
    __shared__ float red[4];
    const int tid = threadIdx.x;
    if (tid < NATOMS * 3) R[tid] = Rs[m * NATOMS * 3 + tid];
    __syncthreads();
    float a2 = 0.0f;
    if (tid < DESC) {
        int i, j;
        pair_ij(tid, i, j);
        const float dx = R[i * 3 + 0] - R[j * 3 + 0];
        const float dy = R[i * 3 + 1] - R[j * 3 + 1];
        const float dz = R[i * 3 + 2] - R[j * 3 + 2];
        const float r2 = dx * dx + dy * dy + dz * dz;
        const float a = QS / sqrtf(r2);
        aT[tid * NM + m] = a;
        a2 = a * a;
    }
    // block reduce a2 (4 waves)
    #pragma unroll
    for (int off = 32; off > 0; off >>= 1) a2 += __shfl_down(a2, off, 64);
    if ((tid & 63) == 0) red[tid >> 6] = a2;
    __syncthreads();
    if (tid == 0) asq[m] = red[0] + red[1] + red[2] + red[3];
}

// B: transpose q*xs_train and Jx to [d][t] layout
__global__ __launch_bounds__(256) void k_transpose(const float* __restrict__ xs_train,
                                                   const float* __restrict__ Jx,
                                                   float* __restrict__ bT,
                                                   float* __restrict__ JxT) {
    const int t = blockIdx.x * 256 + threadIdx.x;
    const int d0 = blockIdx.y * 30;
    #pragma unroll
    for (int k = 0; k < 30; ++k) {
        const int d = d0 + k;
        bT[d * NTRAIN + t] = QS * xs_train[t * DESC + d];
        JxT[d * NTRAIN + t] = Jx[t * DESC + d];
    }
}

// C: pass 1 — per (m,t): dist, dot, weights w1/w2; accumulate Es and S1.
__global__ __launch_bounds__(256) void k_pass1(const float* __restrict__ bT,
                                               const float* __restrict__ JxT,
                                               const float* __restrict__ aT,
                                               const float* __restrict__ asq,
                                               float* __restrict__ w1T,
                                               float* __restrict__ w2T,
                                               float* __restrict__ EsAcc,
                                               float* __restrict__ S1) {
    const int t = blockIdx.x * 256 + threadIdx.x;
    const int m0 = blockIdx.y * 8;
    float P[8], Q[8];
    #pragma unroll
    for (int mi = 0; mi < 8; ++mi) { P[mi] = 0.0f; Q[mi] = 0.0f; }
    float bsq = 0.0f, cj = 0.0f;
    for (int d = 0; d < DESC; ++d) {
        const float bv = bT[d * NTRAIN + t];
        const float jv = JxT[d * NTRAIN + t];
        bsq = fmaf(bv, bv, bsq);
        cj = fmaf(bv, jv, cj);
        const float4 a0 = *reinterpret_cast<const float4*>(aT + d * NM + m0);
        const float4 a1 = *reinterpret_cast<const float4*>(aT + d * NM + m0 + 4);
        P[0] = fmaf(a0.x, bv, P[0]); P[1] = fmaf(a0.y, bv, P[1]);
        P[2] = fmaf(a0.z, bv, P[2]); P[3] = fmaf(a0.w, bv, P[3]);
        P[4] = fmaf(a1.x, bv, P[4]); P[5] = fmaf(a1.y, bv, P[5]);
        P[6] = fmaf(a1.z, bv, P[6]); P[7] = fmaf(a1.w, bv, P[7]);
        Q[0] = fmaf(a0.x, jv, Q[0]); Q[1] = fmaf(a0.y, jv, Q[1]);
        Q[2] = fmaf(a0.z, jv, Q[2]); Q[3] = fmaf(a0.w, jv, Q[3]);
        Q[4] = fmaf(a1.x, jv, Q[4]); Q[5] = fmaf(a1.y, jv, Q[5]);
        Q[6] = fmaf(a1.z, jv, Q[6]); Q[7] = fmaf(a1.w, jv, Q[7]);
    }
    float esv[8], s1v[8];
    float w1o[8], w2o[8];
    #pragma unroll
    for (int mi = 0; mi < 8; ++mi) {
        float dist2 = asq[m0 + mi] + bsq - 2.0f * P[mi];
        dist2 = fmaxf(dist2, 0.0f);
        const float x = sqrtf(dist2);
        const float e = KE * expf(-x);
        const float w2v = e * (1.0f + x);
        const float dotv = Q[mi] - cj;
        const float w1v = e * dotv;
        w1o[mi] = w1v;
        w2o[mi] = w2v;
        esv[mi] = w2v * dotv;
        s1v[mi] = w1v;
    }
    // store w1/w2 in [t][128] layout (two float4 each)
    {
        float4 v;
        v.x = w1o[0]; v.y = w1o[1]; v.z = w1o[2]; v.w = w1o[3];
        *reinterpret_cast<float4*>(w1T + t * NM + m0) = v;
        v.x = w1o[4]; v.y = w1o[5]; v.z = w1o[6]; v.w = w1o[7];
        *reinterpret_cast<float4*>(w1T + t * NM + m0 + 4) = v;
        v.x = w2o[0]; v.y = w2o[1]; v.z = w2o[2]; v.w = w2o[3];
        *reinterpret_cast<float4*>(w2T + t * NM + m0) = v;
        v.x = w2o[4]; v.y = w2o[5]; v.z = w2o[6]; v.w = w2o[7];
        *reinterpret_cast<float4*>(w2T + t * NM + m0 + 4) = v;
    }
    // wave reduce Es and S1 per mi, then one atomic per wave
    #pragma unroll
    for (int off = 32; off > 0; off >>= 1) {
        #pragma unroll
        for (int mi = 0; mi < 8; ++mi) {
            esv[mi] += __shfl_down(esv[mi], off, 64);
            s1v[mi] += __shfl_down(s1v[mi], off, 64);
        }
    }
    if ((threadIdx.x & 63) == 0) {
        #pragma unroll
        for (int mi = 0; mi < 8; ++mi) {
            atomicAdd(&EsAcc[m0 + mi], esv[mi]);
            atomicAdd(&S1[m0 + mi], s1v[mi]);
        }
    }
}

// D: pass 2 — F1acc[m][d] += sum_t w1[t][m]*q*xs_train[t][d];
//            F2acc[m][d] += sum_t w2[t][m]*Jx[t][d]
__global__ __launch_bounds__(256) void k_pass2(const float* __restrict__ xs_train,
                                               const float* __restrict__ Jx,
                                               const float* __restrict__ w1T,
                                               const float* __restrict__ w2T,
                                               float* __restrict__ F1acc,
                                               float* __restrict__ F2acc) {
    const int d = threadIdx.x;
    const int t0 = blockIdx.x * 256;
    const int m0 = blockIdx.y * 8;
    if (d >= DESC) return;
    float G1[8], G2[8];
    #pragma unroll
    for (int mi = 0; mi < 8; ++mi) { G1[mi] = 0.0f; G2[mi] = 0.0f; }
    for (int tt = 0; tt < 256; ++tt) {
        const int t = t0 + tt;
        const float bv = QS * xs_train[t * DESC + d];
        const float jv = Jx[t * DESC + d];
        const float4 wa = *reinterpret_cast<const float4*>(w1T + t * NM + m0);
        const float4 wb = *reinterpret_cast<const float4*>(w1T + t * NM + m0 + 4);
        const float4 va = *reinterpret_cast<const float4*>(w2T + t * NM + m0);
        const float4 vb = *reinterpret_cast<const float4*>(w2T + t * NM + m0 + 4);
        G1[0] = fmaf(wa.x, bv, G1[0]); G1[1] = fmaf(wa.y, bv, G1[1]);
        G1[2] = fmaf(wa.z, bv, G1[2]); G1[3] = fmaf(wa.w, bv, G1[3]);
        G1[4] = fmaf(wb.x, bv, G1[4]); G1[5] = fmaf(wb.y, bv, G1[5]);
        G1[6] = fmaf(wb.z, bv, G1[6]); G1[7] = fmaf(wb.w, bv, G1[7]);
        G2[0] = fmaf(va.x, jv, G2[0]); G2[1] = fmaf(va.y, jv, G2[1]);
        G2[2] = fmaf(va.z, jv, G2[2]); G2[3] = fmaf(va.w, jv, G2[3]);
        G2[4] = fmaf(vb.x, jv, G2[4]); G2[5] = fmaf(vb.y, jv, G2[5]);
        G2[6] = fmaf(vb.z, jv, G2[6]); G2[7] = fmaf(vb.w, jv, G2[7]);
    }
    #pragma unroll
    for (int mi = 0; mi < 8; ++mi) {
        atomicAdd(&F1acc[(m0 + mi) * DESC + d], G1[mi]);
        atomicAdd(&F2acc[(m0 + mi) * DESC + d], G2[mi]);
    }
}

// E: final assembly — coef, force scatter, Es
__global__ __launch_bounds__(256) void k_final(const float* __restrict__ Rs,
                                               const float* __restrict__ aT,
                                               const float* __restrict__ S1,
                                               const float* __restrict__ EsAcc,
                                               const float* __restrict__ F1acc,
                                               const float* __restrict__ F2acc,
                                               float* __restrict__ out) {
    const int m = blockIdx.x;
    __shared__ float R[NATOMS * 3];
    __shared__ float FsL[NATOMS * 3];
    const int tid = threadIdx.x;
    if (tid < NATOMS * 3) {
        R[tid] = Rs[m * NATOMS * 3 + tid];
        FsL[tid] = 0.0f;
    }
    __syncthreads();
    if (tid < DESC) {
        int i, j;
        pair_ij(tid, i, j);
        const float dx = R[i * 3 + 0] - R[j * 3 + 0];
        const float dy = R[i * 3 + 1] - R[j * 3 + 1];
        const float dz = R[i * 3 + 2] - R[j * 3 + 2];
        const float r2 = dx * dx + dy * dy + dz * dz;
        const float rinv = 1.0f / sqrtf(r2);
        const float a = aT[tid * NM + m];  // q/r
        const float F1 = a * S1[m] - F1acc[m * DESC + tid];
        const float Fx = (F1 - F2acc[m * DESC + tid]) * STDC;
        const float coef = Fx * (rinv * rinv * rinv);
        atomicAdd(&FsL[j * 3 + 0], coef * dx);
        atomicAdd(&FsL[j * 3 + 1], coef * dy);
        atomicAdd(&FsL[j * 3 + 2], coef * dz);
        atomicAdd(&FsL[i * 3 + 0], -coef * dx);
        atomicAdd(&FsL[i * 3 + 1], -coef * dy);
        atomicAdd(&FsL[i * 3 + 2], -coef * dz);
    }
    __syncthreads();
    if (tid < NATOMS * 3) out[NM + m * NATOMS * 3 + tid] = FsL[tid];
    if (tid == 0) out[m] = CC + (EsAcc[m] / QS) * STDC;
}

extern "C" void kernel_launch(void* const* d_in, const int* in_sizes, int n_in,
                              void* d_out, int out_size, void* d_ws, size_t ws_size,
                              hipStream_t stream) {
    const float* Rs = (const float*)d_in[0];
    const float* xs_train = (const float*)d_in[1];
    const float* Jx = (const float*)d_in[2];
    float* out = (float*)d_out;
    float* ws = (float*)d_ws;

    float* F1acc = ws;               // 26880
    float* F2acc = ws + 26880;       // 26880
    float* EsAcc = ws + 53760;       // 128
    float* S1 = ws + 53888;          // 128
    float* aT = ws + 54016;          // 26880
    float* asq = ws + 80896;         // 128
    float* bT = ws + 81024;          // 860160
    float* JxT = ws + 941184;        // 860160
    float* w1T = ws + 1801344;       // 524288
    float* w2T = ws + 2325632;       // 524288 -> total 2849920 floats (~11.4 MB)

    // zero accumulators (F1acc,F2acc,EsAcc,S1 are contiguous)
    hipMemsetAsync(ws, 0, (size_t)54016 * sizeof(float), stream);

    k_desc<<<NM, 256, 0, stream>>>(Rs, aT, asq);
    k_transpose<<<dim3(NTRAIN / 256, 7), 256, 0, stream>>>(xs_train, Jx, bT, JxT);
    k_pass1<<<dim3(NTRAIN / 256, NM / 8), 256, 0, stream>>>(bT, JxT, aT, asq, w1T, w2T,
                                                            EsAcc, S1);
    k_pass2<<<dim3(NTRAIN / 256, NM / 8), 256, 0, stream>>>(xs_train, Jx, w1T, w2T,
                                                            F1acc, F2acc);
    k_final<<<NM, 256, 0, stream>>>(Rs, aT, S1, EsAcc, F1acc, F2acc, out);
}